// Round 2
// baseline (250.098 us; speedup 1.0000x reference)
//
#include <hip/hip_runtime.h>
#include <hip/hip_bf16.h>

// Problem constants: N=32, C=3, H=W=512, A=512, SCALE=1, ITERS=5, thr0=4.0f.
#define AN 512
#define NB 32
#define HW 512

__device__ __forceinline__ float waveMax(float v) {
    #pragma unroll
    for (int off = 32; off > 0; off >>= 1) v = fmaxf(v, __shfl_xor(v, off, 64));
    return v;
}
__device__ __forceinline__ float waveSum(float v) {
    #pragma unroll
    for (int off = 32; off > 0; off >>= 1) v += __shfl_xor(v, off, 64);
    return v;
}

// ---------------------------------------------------------------------------
// Kernel 1: water-fill + inverse-CDF coords. One block per sample.
// Barrier-minimized: 2 barriers per water-fill iter (separate max/sum LDS
// arrays), shfl-based wave scan (no barriers) + 1 cross-wave combine, fused
// x/y binary searches. NOTE: search space is 513 answers -> 9 unrolled
// halvings leave a size-<=1 interval; the guarded fixup below is the exact
// 10th probe (dropping it was R1's off-by-one correctness bug).
// ---------------------------------------------------------------------------
__global__ __launch_bounds__(512) void waterfill_coords_kernel(
    const float* __restrict__ attx, const float* __restrict__ atty,
    float* __restrict__ gx, float* __restrict__ gy)
{
    __shared__ float axs[AN], ays[AN], csx[AN], csy[AN];
    __shared__ float wmx[8], wmy[8], wsx[8], wsy[8], wtx[8], wty[8];
    const int n = blockIdx.x;
    const int t = threadIdx.x;
    const int wid = t >> 6;
    const int lane = t & 63;

    float ax = attx[n * AN + t] * 512.0f;
    float ay = atty[n * AN + t] * 512.0f;

    #pragma unroll
    for (int j = 0; j < 5; ++j) {
        float mx = waveMax(ax), my = waveMax(ay);
        if (lane == 0) { wmx[wid] = mx; wmy[wid] = my; }
        __syncthreads();                              // barrier 1
        float Mx = wmx[0], My = wmy[0];
        #pragma unroll
        for (int i = 1; i < 8; ++i) { Mx = fmaxf(Mx, wmx[i]); My = fmaxf(My, wmy[i]); }
        float thr = fminf(Mx, My);
        if (j == 0) thr = fminf(thr, 4.0f);
        ax = fminf(ax, thr);
        ay = fminf(ay, thr);

        float sx = waveSum(ax), sy = waveSum(ay);
        if (lane == 0) { wsx[wid] = sx; wsy[wid] = sy; }
        __syncthreads();                              // barrier 2
        float Sx = 0.0f, Sy = 0.0f;
        #pragma unroll
        for (int i = 0; i < 8; ++i) { Sx += wsx[i]; Sy += wsy[i]; }
        ax += (512.0f - Sx) * (1.0f / 512.0f);
        ay += (512.0f - Sy) * (1.0f / 512.0f);
        // iter j+1's wmx writes are fenced from iter j's wmx reads by barrier 2
    }

    if (t == 0) { ax = 1.0f; ay = 1.0f; }
    axs[t] = ax; ays[t] = ay;

    // inclusive scan: per-wave shfl scan (no barriers) + cross-wave prefix
    float cx = ax, cy = ay;
    #pragma unroll
    for (int off = 1; off < 64; off <<= 1) {
        float ux = __shfl_up(cx, off, 64);
        float uy = __shfl_up(cy, off, 64);
        if (lane >= off) { cx += ux; cy += uy; }
    }
    if (lane == 63) { wtx[wid] = cx; wty[wid] = cy; }
    __syncthreads();
    float px = 0.0f, py = 0.0f;
    #pragma unroll
    for (int i = 0; i < 8; ++i) {
        if (i < wid) { px += wtx[i]; py += wty[i]; }
    }
    cx += px; cy += py;
    csx[t] = cx; csy[t] = cy;
    __syncthreads();

    // fused inverse-CDF searches (x chain and y chain independent -> ILP)
    const float stepx = csx[AN - 1] * (1.0f / 512.0f);
    const float stepy = csy[AN - 1] * (1.0f / 512.0f);
    const float tvx = (float)(t + 1) * stepx;
    const float tvy = (float)(t + 1) * stepy;
    int lox = 0, hix = AN, loy = 0, hiy = AN;
    #pragma unroll
    for (int s = 0; s < 9; ++s) {
        const int mx_ = (lox + hix) >> 1;
        const int my_ = (loy + hiy) >> 1;
        const float vx = csx[mx_];
        const float vy = csy[my_];
        if (vx < tvx) lox = mx_ + 1; else hix = mx_;
        if (vy < tvy) loy = my_ + 1; else hiy = my_;
    }
    // exact 10th probe: interval size is now 0 or 1
    if (lox < hix && csx[lox] < tvx) ++lox;
    if (loy < hiy && csy[loy] < tvy) ++loy;
    {
        const int j = lox > (AN - 1) ? (AN - 1) : lox;
        const float prev = (j > 0) ? csx[j - 1] : 0.0f;
        const float frac = (tvx - prev) / fmaxf(axs[j], 1e-12f);
        gy[n * AN + t] = ((float)j + frac) * (2.0f / 512.0f) - 1.0f;
    }
    {
        const int j = loy > (AN - 1) ? (AN - 1) : loy;
        const float prev = (j > 0) ? csy[j - 1] : 0.0f;
        const float frac = (tvy - prev) / fmaxf(ays[j], 1e-12f);
        gx[n * AN + t] = ((float)j + frac) * (2.0f / 512.0f) - 1.0f;
    }
}

// ---------------------------------------------------------------------------
// Kernel 2: separable bilinear grid-sample via LDS row staging.
// One block per (ho, n). XCD-bijective swizzle: each XCD gets 4 contiguous
// samples (3 MB/sample < 4 MB L2) so the ~2x y-row re-reads are L2-hits.
// Staging uses global_load_lds width-16 (no VGPR round-trip); LDS dest is
// wave-uniform base + lane*16 (row0/col0 derived from wid only).
// ---------------------------------------------------------------------------
__global__ __launch_bounds__(256) void grid_sample_kernel(
    const float* __restrict__ data, const float* __restrict__ gx,
    const float* __restrict__ gy, float* __restrict__ outS,
    float* __restrict__ outG)
{
    __shared__ __align__(16) float rows[6][HW];   // [y0: c0,c1,c2 | y1: c0,c1,c2][x]
    const int t   = threadIdx.x;
    const int lid = blockIdx.x;
    // bijective XCD swizzle: 16384 blocks, 8 XCDs, 2048 contiguous wg per XCD
    const int wg  = (lid & 7) * 2048 + (lid >> 3);
    const int n   = wg >> 9;
    const int ho  = wg & 511;
    const int wid = t >> 6;
    const int lane = t & 63;

    const float gyv = gy[n * AN + ho];
    const float y   = (gyv + 1.0f) * 256.0f - 0.5f;
    const float y0f = floorf(y);
    const float wy1 = y - y0f, wy0 = 1.0f - wy1;
    const float vy0 = ((y0f >= 0.0f) & (y0f < 512.0f)) ? 1.0f : 0.0f;
    const float vy1 = ((y0f >= -1.0f) & (y0f < 511.0f)) ? 1.0f : 0.0f;
    const int y0 = (int)fminf(fmaxf(y0f, 0.0f), 511.0f);
    const int y1 = (int)fminf(fmaxf(y0f + 1.0f, 0.0f), 511.0f);

    // stage 6 source rows (2 y x 3 c) = 768 float4, 3 per thread, async to LDS
    const float* base = data + (size_t)n * 3 * HW * HW;
    #pragma unroll
    for (int r = 0; r < 3; ++r) {
        const int idx0 = r * 256 + (wid << 6);   // wave-uniform
        const int row0 = idx0 >> 7;              // 0..5, wave-uniform
        const int col0 = idx0 & 127;             // float4 index, wave-uniform
        const int yy   = (row0 < 3) ? y0 : y1;
        const int c    = (row0 < 3) ? row0 : row0 - 3;
        const float* g = base + ((size_t)c * HW + yy) * HW + ((col0 + lane) << 2);
        __builtin_amdgcn_global_load_lds(
            (const __attribute__((address_space(1))) void*)g,
            (__attribute__((address_space(3))) void*)(&rows[row0][col0 << 2]),
            16, 0, 0);
    }
    __syncthreads();   // drains vmcnt(0) -> all global_load_lds complete

    // 2 consecutive px per thread
    const float2 gx2 = ((const float2*)(gx + n * AN))[t];
    const float xg[2] = {gx2.x, gx2.y};
    float res[3][2];

    #pragma unroll
    for (int k = 0; k < 2; ++k) {
        const float gxv = xg[k];
        const float x   = (gxv + 1.0f) * 256.0f - 0.5f;
        const float x0f = floorf(x);
        const float wx1 = x - x0f, wx0 = 1.0f - wx1;
        const float vx0 = ((x0f >= 0.0f) & (x0f < 512.0f)) ? 1.0f : 0.0f;
        const float vx1 = ((x0f >= -1.0f) & (x0f < 511.0f)) ? 1.0f : 0.0f;
        const int x0 = (int)fminf(fmaxf(x0f, 0.0f), 511.0f);
        const int x1 = (int)fminf(fmaxf(x0f + 1.0f, 0.0f), 511.0f);
        const float w00 = wx0 * wy0 * vx0 * vy0;
        const float w10 = wx1 * wy0 * vx1 * vy0;
        const float w01 = wx0 * wy1 * vx0 * vy1;
        const float w11 = wx1 * wy1 * vx1 * vy1;
        #pragma unroll
        for (int c = 0; c < 3; ++c) {
            res[c][k] = rows[c][x0] * w00 + rows[c][x1] * w10
                      + rows[3 + c][x0] * w01 + rows[3 + c][x1] * w11;
        }
    }

    const int wo = 2 * t;
    const size_t o = (((size_t)n * 3) * HW + ho) * HW + wo;
    #pragma unroll
    for (int c = 0; c < 3; ++c)
        *(float2*)(outS + o + (size_t)c * HW * HW) = make_float2(res[c][0], res[c][1]);

    *(float4*)(outG + (((size_t)n * HW + ho) * HW + wo) * 2) =
        make_float4(gx2.x, gyv, gx2.y, gyv);
}

extern "C" void kernel_launch(void* const* d_in, const int* in_sizes, int n_in,
                              void* d_out, int out_size, void* d_ws, size_t ws_size,
                              hipStream_t stream) {
    const float* data = (const float*)d_in[0];   // (32,3,512,512)
    const float* attx = (const float*)d_in[1];   // (32,512)
    const float* atty = (const float*)d_in[2];   // (32,512)

    float* gx = (float*)d_ws;            // (32,512) width coords
    float* gy = gx + NB * AN;            // (32,512) height coords

    float* outS = (float*)d_out;                          // sampled (32,3,512,512)
    float* outG = outS + (size_t)NB * 3 * HW * HW;        // grid (32,512,512,2)

    waterfill_coords_kernel<<<NB, AN, 0, stream>>>(attx, atty, gx, gy);

    grid_sample_kernel<<<NB * HW, 256, 0, stream>>>(data, gx, gy, outS, outG);
}